// Round 1
// baseline (588.774 us; speedup 1.0000x reference)
//
#include <hip/hip_runtime.h>
#include <hip/hip_bf16.h>
#include <math.h>

#define BB 128
#define NN 12000
#define NIN 4000
#define NFN 7000
#define NOMIC 3600
#define FC 56000
#define EE 57000
#define LAT 100

// ---------------- transpose x (B,N) -> xT (N,B) ----------------
__global__ void k_transpose(const float* __restrict__ x, float* __restrict__ xT) {
  __shared__ float t[32][33];
  int n0 = blockIdx.x * 32, b0 = blockIdx.y * 32;
  int tx = threadIdx.x, ty = threadIdx.y;
#pragma unroll
  for (int s = 0; s < 4; s++) {
    int b = b0 + ty + s * 8;
    int n = n0 + tx;
    t[ty + s * 8][tx] = x[b * NN + n];  // t[b_local][n_local]
  }
  __syncthreads();
#pragma unroll
  for (int s = 0; s < 4; s++) {
    int n = n0 + ty + s * 8;
    int b = b0 + tx;
    xT[n * BB + b] = t[tx][ty + s * 8];
  }
}

// ---------------- AE layer 1 partial: h_raw[b,j] += sum_k xo[b,k]*W1[k,j] ----------------
__global__ void k_ae1(const float* __restrict__ x, const float* __restrict__ W1,
                      float* __restrict__ h) {
  __shared__ float xs[900];
  int b = blockIdx.x, kc = blockIdx.y;
  int k0 = kc * 900;
  for (int k = threadIdx.x; k < 900; k += 128) xs[k] = x[b * NN + k0 + k];
  __syncthreads();
  int j = threadIdx.x;
  if (j < LAT) {
    float acc = 0.f;
#pragma unroll 4
    for (int kk = 0; kk < 900; kk++) acc += xs[kk] * W1[(k0 + kk) * LAT + j];
    atomicAdd(&h[b * LAT + j], acc);
  }
}

// ---------------- build xeT[e*128+b] from xT / src ----------------
__global__ void k_build_xe(const float* __restrict__ xT, const int* __restrict__ src,
                           float* __restrict__ xeT) {
  int idx = blockIdx.x * 256 + threadIdx.x;
  if (idx >= EE * BB) return;
  int e = idx >> 7, b = idx & 127;
  int s = src[e];
  xeT[idx] = (s < NOMIC) ? 0.f : xT[s * BB + b];
}

// ---------------- map[e] = fe-position i (else -1, pre-set by memset 0xFF) ----------------
__global__ void k_map(const int* __restrict__ w3_cols, int* __restrict__ map, int n_fe) {
  int i = blockIdx.x * 256 + threadIdx.x;
  if (i < n_fe) map[w3_cols[i * 8]] = i;
}

// ---------------- AE layer 2: z = elu(h+b_ae1) @ W2 + b_ae2, write zT, partial LN stats ----------------
__launch_bounds__(256)
__global__ void k_ae2(const float* __restrict__ h, const float* __restrict__ b_ae1,
                      const float* __restrict__ W2, const float* __restrict__ b_ae2,
                      float* __restrict__ zT, float* __restrict__ red) {
  __shared__ __align__(16) float hh[LAT * BB];  // hh[k*128+b]
  __shared__ float lred[256];                   // [b*2]=sum, [b*2+1]=sumsq
  int tid = threadIdx.x;
  lred[tid] = 0.f;
  for (int idx = tid; idx < LAT * BB; idx += 256) {
    int b = idx / LAT, k = idx % LAT;
    float v = h[idx] + b_ae1[k];
    v = v > 0.f ? v : expm1f(v);
    hh[k * BB + b] = v;
  }
  __syncthreads();
  int j = blockIdx.x * 32 + (tid >> 3);
  int bb = (tid & 7) * 16;
  float acc[16];
#pragma unroll
  for (int i = 0; i < 16; i++) acc[i] = 0.f;
  const float* hp = &hh[bb];
  for (int k = 0; k < LAT; k++) {
    float w = W2[k * FC + j];
    const float4* h4 = (const float4*)(hp + k * BB);
    float4 a0 = h4[0], a1 = h4[1], a2 = h4[2], a3 = h4[3];
    acc[0] += a0.x * w; acc[1] += a0.y * w; acc[2] += a0.z * w; acc[3] += a0.w * w;
    acc[4] += a1.x * w; acc[5] += a1.y * w; acc[6] += a1.z * w; acc[7] += a1.w * w;
    acc[8] += a2.x * w; acc[9] += a2.y * w; acc[10] += a2.z * w; acc[11] += a2.w * w;
    acc[12] += a3.x * w; acc[13] += a3.y * w; acc[14] += a3.z * w; acc[15] += a3.w * w;
  }
  float bj = b_ae2[j];
#pragma unroll
  for (int i = 0; i < 16; i++) acc[i] += bj;
  float4* zp = (float4*)&zT[j * BB + bb];
  zp[0] = make_float4(acc[0], acc[1], acc[2], acc[3]);
  zp[1] = make_float4(acc[4], acc[5], acc[6], acc[7]);
  zp[2] = make_float4(acc[8], acc[9], acc[10], acc[11]);
  zp[3] = make_float4(acc[12], acc[13], acc[14], acc[15]);
#pragma unroll
  for (int i = 0; i < 16; i++) {
    atomicAdd(&lred[(bb + i) * 2], acc[i]);
    atomicAdd(&lred[(bb + i) * 2 + 1], acc[i] * acc[i]);
  }
  __syncthreads();
  atomicAdd(&red[tid], lred[tid]);
}

// ---------------- s = sigmoid(layernorm(z)) ----------------
__global__ void k_s(const float* __restrict__ zT, const float* __restrict__ red,
                    float* __restrict__ sT) {
  int idx = blockIdx.x * 256 + threadIdx.x;
  if (idx >= FC * BB) return;
  int b = idx & 127;
  float mu = red[b * 2] * (1.f / FC);
  float var = red[b * 2 + 1] * (1.f / FC) - mu * mu;
  float t = (zT[idx] - mu) * rsqrtf(var + 1e-5f);
  sT[idx] = 1.f / (1.f + expf(-t));
}

// ---------------- layer part 1: hfc = elu(s * groupLN(8x8 matmul(xe) + b1)) ----------------
__launch_bounds__(256)
__global__ void k_layer1(const float* __restrict__ xeT, const float* __restrict__ w1l,
                         const float* __restrict__ b1l, const float* __restrict__ sT,
                         float* __restrict__ hfcT) {
  __shared__ __align__(16) float wsm[2][64];
  __shared__ float bsm[2][8];
  int tid = threadIdx.x;
  int fs = tid >> 7;  // 0..1
  int b = tid & 127;
  int f = blockIdx.x * 2 + fs;
  if (tid < 128) wsm[tid >> 6][tid & 63] = w1l[blockIdx.x * 128 + tid];
  if (tid >= 128 && tid < 144) {
    int q = tid - 128;
    bsm[q >> 3][q & 7] = b1l[blockIdx.x * 16 + q];
  }
  __syncthreads();
  float xv[8];
#pragma unroll
  for (int k = 0; k < 8; k++) xv[k] = xeT[(f * 8 + k) * BB + b];
  float acc[8];
#pragma unroll
  for (int c = 0; c < 8; c++) acc[c] = bsm[fs][c];
#pragma unroll
  for (int k = 0; k < 8; k++) {
    const float4* wp = (const float4*)&wsm[fs][k * 8];
    float4 w0 = wp[0], w1 = wp[1];
    acc[0] += xv[k] * w0.x; acc[1] += xv[k] * w0.y;
    acc[2] += xv[k] * w0.z; acc[3] += xv[k] * w0.w;
    acc[4] += xv[k] * w1.x; acc[5] += xv[k] * w1.y;
    acc[6] += xv[k] * w1.z; acc[7] += xv[k] * w1.w;
  }
  float mu = 0.f;
#pragma unroll
  for (int c = 0; c < 8; c++) mu += acc[c];
  mu *= 0.125f;
  float var = 0.f;
#pragma unroll
  for (int c = 0; c < 8; c++) { float d = acc[c] - mu; var += d * d; }
  var *= 0.125f;
  float sc = rsqrtf(var + 1e-5f);
#pragma unroll
  for (int c = 0; c < 8; c++) {
    float v = (acc[c] - mu) * sc;
    float sv = sT[(f * 8 + c) * BB + b];
    float hv = sv * v;
    hv = hv > 0.f ? hv : expm1f(hv);
    hfcT[(f * 8 + c) * BB + b] = hv;
  }
}

// ---------------- layer part 2: xe = (fe? dot8(hfc[src], w3) : 0) + b3 + xe ----------------
__launch_bounds__(256)
__global__ void k_layer2(const float* __restrict__ hfcT, const float* __restrict__ w3l,
                         const float* __restrict__ b3l, const int* __restrict__ map,
                         const int* __restrict__ src, float* __restrict__ xeT) {
  __shared__ float wsm[2][8];
  int tid = threadIdx.x;
  int es = tid >> 7;
  int b = tid & 127;
  int e = blockIdx.x * 2 + es;
  if (tid < 16) {
    int q = tid;
    int ee = blockIdx.x * 2 + (q >> 3);
    int ii = map[ee];
    wsm[q >> 3][q & 7] = (ii >= 0) ? w3l[ii * 8 + (q & 7)] : 0.f;
  }
  __syncthreads();
  int i = map[e];
  float rv = b3l[e] + xeT[e * BB + b];
  if (i >= 0) {
    int g = src[e] - NIN;
    float a = 0.f;
#pragma unroll
    for (int c = 0; c < 8; c++) a += hfcT[(g * 8 + c) * BB + b] * wsm[es][c];
    rv += a;
  }
  xeT[e * BB + b] = rv;
}

// ---------------- output: out[b, 11000+j] = xe[b, 56000+j] / 4 ----------------
__global__ void k_out(const float* __restrict__ xeT, float* __restrict__ out) {
  __shared__ float t[32][33];
  int j0 = blockIdx.x * 32, b0 = blockIdx.y * 32;
  int tx = threadIdx.x, ty = threadIdx.y;
#pragma unroll
  for (int s2 = 0; s2 < 4; s2++) {
    int j = j0 + ty + s2 * 8;
    if (j < 1000) t[ty + s2 * 8][tx] = xeT[(FC + j) * BB + b0 + tx];
  }
  __syncthreads();
#pragma unroll
  for (int s2 = 0; s2 < 4; s2++) {
    int b = b0 + ty + s2 * 8;
    int j = j0 + tx;
    if (j < 1000) out[b * NN + 11000 + j] = t[tx][ty + s2 * 8] * 0.25f;
  }
}

extern "C" void kernel_launch(void* const* d_in, const int* in_sizes, int n_in,
                              void* d_out, int out_size, void* d_ws, size_t ws_size,
                              hipStream_t stream) {
  const float* x = (const float*)d_in[0];
  const float* W_ae1 = (const float*)d_in[1];
  const float* b_ae1 = (const float*)d_in[2];
  const float* W_ae2 = (const float*)d_in[3];
  const float* b_ae2 = (const float*)d_in[4];
  const float* w1_vals = (const float*)d_in[5];
  const float* b1 = (const float*)d_in[6];
  const float* w3_vals = (const float*)d_in[7];
  const float* b3 = (const float*)d_in[8];
  const int* src = (const int*)d_in[9];
  const int* w3_cols = (const int*)d_in[14];

  int nnz3 = in_sizes[13];  // w3_rows element count
  int n_fe = nnz3 / 8;

  float* W = (float*)d_ws;
  float* h_raw = W + 0;            // 12800
  float* red = W + 12800;          // 256
  int* map = (int*)(W + 13056);    // 57000 ints
  float* xT = W + 70144;           // 1,536,000
  float* sT = W + 1606144;         // 7,168,000
  float* xeT = W + 8774144;        // 7,296,000
  float* zT = W + 16070144;        // 7,168,000 (reused as hfcT)

  hipMemsetAsync(h_raw, 0, 12800 * sizeof(float), stream);
  hipMemsetAsync(red, 0, 256 * sizeof(float), stream);
  hipMemsetAsync(map, 0xFF, EE * sizeof(int), stream);
  hipMemsetAsync(d_out, 0, (size_t)out_size * sizeof(float), stream);

  k_transpose<<<dim3(NN / 32, BB / 32), dim3(32, 8), 0, stream>>>(x, xT);
  k_ae1<<<dim3(BB, 4), 128, 0, stream>>>(x, W_ae1, h_raw);
  k_build_xe<<<(EE * BB) / 256, 256, 0, stream>>>(xT, src, xeT);
  k_map<<<(n_fe + 255) / 256, 256, 0, stream>>>(w3_cols, map, n_fe);
  k_ae2<<<FC / 32, 256, 0, stream>>>(h_raw, b_ae1, W_ae2, b_ae2, zT, red);
  k_s<<<(FC * BB) / 256, 256, 0, stream>>>(zT, red, sT);
  for (int l = 0; l < 4; l++) {
    k_layer1<<<NFN / 2, 256, 0, stream>>>(xeT, w1_vals + (size_t)l * 448000,
                                          b1 + (size_t)l * FC, sT, zT);
    k_layer2<<<EE / 2, 256, 0, stream>>>(zT, w3_vals + (size_t)l * nnz3,
                                         b3 + (size_t)l * EE, map, src, xeT);
  }
  k_out<<<dim3(32, 4), dim3(32, 8), 0, stream>>>(xeT, (float*)d_out);
}

// Round 3
// 478.737 us; speedup vs baseline: 1.2298x; 1.2298x over previous
//
#include <hip/hip_runtime.h>
#include <hip/hip_bf16.h>
#include <math.h>

#define BB 128
#define NN 12000
#define NIN 4000
#define NFN 7000
#define NOMIC 3600
#define FC 56000
#define EE 57000
#define LAT 100

// ---------------- transpose x (B,N) -> xT (N,B) ----------------
__global__ void k_transpose(const float* __restrict__ x, float* __restrict__ xT) {
  __shared__ float t[32][33];
  int n0 = blockIdx.x * 32, b0 = blockIdx.y * 32;
  int tx = threadIdx.x, ty = threadIdx.y;
#pragma unroll
  for (int s = 0; s < 4; s++) {
    int b = b0 + ty + s * 8;
    int n = n0 + tx;
    t[ty + s * 8][tx] = x[b * NN + n];
  }
  __syncthreads();
#pragma unroll
  for (int s = 0; s < 4; s++) {
    int n = n0 + ty + s * 8;
    int b = b0 + tx;
    xT[n * BB + b] = t[tx][ty + s * 8];
  }
}

// ---------------- AE layer 1 partial: h_raw[b,j] += sum_k xo[b,k]*W1[k,j] ----------------
__global__ void k_ae1(const float* __restrict__ x, const float* __restrict__ W1,
                      float* __restrict__ h) {
  __shared__ float xs[900];
  int b = blockIdx.x, kc = blockIdx.y;
  int k0 = kc * 900;
  for (int k = threadIdx.x; k < 900; k += 128) xs[k] = x[b * NN + k0 + k];
  __syncthreads();
  int j = threadIdx.x;
  if (j < LAT) {
    float acc = 0.f;
#pragma unroll 4
    for (int kk = 0; kk < 900; kk++) acc += xs[kk] * W1[(k0 + kk) * LAT + j];
    atomicAdd(&h[b * LAT + j], acc);
  }
}

// ---------------- build xeT[e*128+b] from xT / src ----------------
__global__ void k_build_xe(const float* __restrict__ xT, const int* __restrict__ src,
                           float* __restrict__ xeT) {
  int idx = blockIdx.x * 256 + threadIdx.x;
  if (idx >= EE * BB) return;
  int e = idx >> 7, b = idx & 127;
  int s = src[e];
  xeT[idx] = (s < NOMIC) ? 0.f : xT[s * BB + b];
}

// ---------------- map[e] = fe-position i (else -1, pre-set by memset 0xFF) ----------------
__global__ void k_map(const int* __restrict__ w3_cols, int* __restrict__ map, int n_fe) {
  int i = blockIdx.x * 256 + threadIdx.x;
  if (i < n_fe) map[w3_cols[i * 8]] = i;
}

// ---------------- AE layer 2 GEMM: zT[j*128+b] = elu(h+b1) @ W2 + b2, + LN partial sums --
// 128x128 tile per block, 8b x 8j per thread. hh in LDS (broadcast reads),
// W2 streamed from global (coalesced dwordx4, block-exclusive columns).
__launch_bounds__(256)
__global__ void k_ae2(const float* __restrict__ h_raw, const float* __restrict__ b_ae1,
                      const float* __restrict__ W2, const float* __restrict__ b_ae2,
                      float* __restrict__ zT, float* __restrict__ red) {
  __shared__ __align__(16) float hh[LAT * BB];  // hh[k*128+b], 51.2 KB
  __shared__ float lred[256];
  int tid = threadIdx.x;
  lred[tid] = 0.f;
  for (int idx = tid; idx < LAT * BB; idx += 256) {
    int b = idx / LAT, k = idx - b * LAT;  // h_raw layout [b*LAT+k]
    float v = h_raw[idx] + b_ae1[k];
    v = v > 0.f ? v : expm1f(v);
    hh[k * BB + b] = v;
  }
  __syncthreads();

  int tj = tid & 15;          // j-group: 16 x 8 j
  int tb = tid >> 4;          // b-group: 16 x 8 b
  int j0 = blockIdx.x * 128;
  if (j0 + 128 > FC) j0 = FC - 128;  // last block overlaps (grid=438, FC=56000)
  bool cred = (blockIdx.x < 437) || (tj >= 8);  // avoid double-count in LN sums

  float acc[8][8];
#pragma unroll
  for (int i = 0; i < 8; i++)
#pragma unroll
    for (int j = 0; j < 8; j++) acc[i][j] = 0.f;

  const float* hp = &hh[tb * 8];
  const float* wp = &W2[j0 + tj * 8];
#pragma unroll 2
  for (int k = 0; k < LAT; k++) {
    float4 h0 = *(const float4*)(hp + k * BB);
    float4 h1 = *(const float4*)(hp + k * BB + 4);
    float4 w0 = *(const float4*)(wp + (size_t)k * FC);
    float4 w1 = *(const float4*)(wp + (size_t)k * FC + 4);
    float ah[8] = {h0.x, h0.y, h0.z, h0.w, h1.x, h1.y, h1.z, h1.w};
    float aw[8] = {w0.x, w0.y, w0.z, w0.w, w1.x, w1.y, w1.z, w1.w};
#pragma unroll
    for (int i = 0; i < 8; i++)
#pragma unroll
      for (int j = 0; j < 8; j++) acc[i][j] += ah[i] * aw[j];
  }

  // + bias
  float4 bb0 = *(const float4*)&b_ae2[j0 + tj * 8];
  float4 bb1 = *(const float4*)&b_ae2[j0 + tj * 8 + 4];
  float bw[8] = {bb0.x, bb0.y, bb0.z, bb0.w, bb1.x, bb1.y, bb1.z, bb1.w};
#pragma unroll
  for (int i = 0; i < 8; i++)
#pragma unroll
    for (int j = 0; j < 8; j++) acc[i][j] += bw[j];

  // store zT
#pragma unroll
  for (int j = 0; j < 8; j++) {
    float4* zp = (float4*)&zT[(size_t)(j0 + tj * 8 + j) * BB + tb * 8];
    zp[0] = make_float4(acc[0][j], acc[1][j], acc[2][j], acc[3][j]);
    zp[1] = make_float4(acc[4][j], acc[5][j], acc[6][j], acc[7][j]);
  }

  // LN partial sums per b-row
  if (cred) {
#pragma unroll
    for (int i = 0; i < 8; i++) {
      float s = 0.f, q = 0.f;
#pragma unroll
      for (int j = 0; j < 8; j++) { s += acc[i][j]; q += acc[i][j] * acc[i][j]; }
      int b = tb * 8 + i;
      atomicAdd(&lred[b * 2], s);
      atomicAdd(&lred[b * 2 + 1], q);
    }
  }
  __syncthreads();
  atomicAdd(&red[tid], lred[tid]);
}

// ---------------- stats: mu[b], inv_sigma[b] ----------------
__global__ void k_stat(const float* __restrict__ red, float* __restrict__ stat) {
  int b = threadIdx.x;
  float mu = red[b * 2] * (1.f / FC);
  float var = red[b * 2 + 1] * (1.f / FC) - mu * mu;
  stat[b * 2] = mu;
  stat[b * 2 + 1] = rsqrtf(var + 1e-5f);
}

// ---------------- s = sigmoid(layernorm(z)), bf16 out, 8 elems/thread ----------------
__global__ void k_s(const float* __restrict__ zT, const float* __restrict__ stat,
                    __hip_bfloat16* __restrict__ sT) {
  int base = (blockIdx.x * 256 + threadIdx.x) * 8;
  float4 z0 = *(const float4*)&zT[base];
  float4 z1 = *(const float4*)&zT[base + 4];
  float zv[8] = {z0.x, z0.y, z0.z, z0.w, z1.x, z1.y, z1.z, z1.w};
  union { ushort u[8]; uint4 v; } pk;
  int b0 = base & 127;
#pragma unroll
  for (int i = 0; i < 8; i++) {
    float mu = stat[(b0 + i) * 2];
    float isg = stat[(b0 + i) * 2 + 1];
    float t = (zv[i] - mu) * isg;
    float sv = 1.f / (1.f + expf(-t));
    __hip_bfloat16 hb = __float2bfloat16(sv);
    pk.u[i] = *(ushort*)&hb;
  }
  *(uint4*)&sT[base] = pk.v;
}

// ---------------- layer part 1: hfc = elu(s * groupLN(8x8 matmul(xe) + b1)) ----------------
__launch_bounds__(256)
__global__ void k_layer1(const float* __restrict__ xeT, const float* __restrict__ w1l,
                         const float* __restrict__ b1l, const __hip_bfloat16* __restrict__ sT,
                         __hip_bfloat16* __restrict__ hfcT) {
  __shared__ __align__(16) float wsm[2][64];
  __shared__ float bsm[2][8];
  int tid = threadIdx.x;
  int fs = tid >> 7;
  int b = tid & 127;
  int f = blockIdx.x * 2 + fs;
  if (tid < 128) wsm[tid >> 6][tid & 63] = w1l[blockIdx.x * 128 + tid];
  if (tid >= 128 && tid < 144) {
    int q = tid - 128;
    bsm[q >> 3][q & 7] = b1l[blockIdx.x * 16 + q];
  }
  __syncthreads();
  float xv[8];
#pragma unroll
  for (int k = 0; k < 8; k++) xv[k] = xeT[(f * 8 + k) * BB + b];
  float acc[8];
#pragma unroll
  for (int c = 0; c < 8; c++) acc[c] = bsm[fs][c];
#pragma unroll
  for (int k = 0; k < 8; k++) {
    const float4* wp = (const float4*)&wsm[fs][k * 8];
    float4 w0 = wp[0], w1 = wp[1];
    acc[0] += xv[k] * w0.x; acc[1] += xv[k] * w0.y;
    acc[2] += xv[k] * w0.z; acc[3] += xv[k] * w0.w;
    acc[4] += xv[k] * w1.x; acc[5] += xv[k] * w1.y;
    acc[6] += xv[k] * w1.z; acc[7] += xv[k] * w1.w;
  }
  float mu = 0.f;
#pragma unroll
  for (int c = 0; c < 8; c++) mu += acc[c];
  mu *= 0.125f;
  float var = 0.f;
#pragma unroll
  for (int c = 0; c < 8; c++) { float d = acc[c] - mu; var += d * d; }
  var *= 0.125f;
  float sc = rsqrtf(var + 1e-5f);
#pragma unroll
  for (int c = 0; c < 8; c++) {
    float v = (acc[c] - mu) * sc;
    float sv = __bfloat162float(sT[(f * 8 + c) * BB + b]);
    float hv = sv * v;
    hv = hv > 0.f ? hv : expm1f(hv);
    hfcT[(f * 8 + c) * BB + b] = __float2bfloat16(hv);
  }
}

// ---------------- layer part 2: xe = (fe? dot8(hfc[src], w3) : 0) + b3 + xe ----------------
__launch_bounds__(256)
__global__ void k_layer2(const __hip_bfloat16* __restrict__ hfcT, const float* __restrict__ w3l,
                         const float* __restrict__ b3l, const int* __restrict__ map,
                         const int* __restrict__ src, float* __restrict__ xeT) {
  __shared__ float wsm[2][8];
  int tid = threadIdx.x;
  int es = tid >> 7;
  int b = tid & 127;
  int e = blockIdx.x * 2 + es;
  if (tid < 16) {
    int q = tid;
    int ee = blockIdx.x * 2 + (q >> 3);
    int ii = map[ee];
    wsm[q >> 3][q & 7] = (ii >= 0) ? w3l[ii * 8 + (q & 7)] : 0.f;
  }
  __syncthreads();
  int i = map[e];
  float rv = b3l[e] + xeT[e * BB + b];
  if (i >= 0) {
    int g = src[e] - NIN;
    float a = 0.f;
#pragma unroll
    for (int c = 0; c < 8; c++)
      a += __bfloat162float(hfcT[(g * 8 + c) * BB + b]) * wsm[es][c];
    rv += a;
  }
  xeT[e * BB + b] = rv;
}

// ---------------- output: out[b, 11000+j] = xe[b, 56000+j] / 4 ----------------
__global__ void k_out(const float* __restrict__ xeT, float* __restrict__ out) {
  __shared__ float t[32][33];
  int j0 = blockIdx.x * 32, b0 = blockIdx.y * 32;
  int tx = threadIdx.x, ty = threadIdx.y;
#pragma unroll
  for (int s2 = 0; s2 < 4; s2++) {
    int j = j0 + ty + s2 * 8;
    if (j < 1000) t[ty + s2 * 8][tx] = xeT[(FC + j) * BB + b0 + tx];
  }
  __syncthreads();
#pragma unroll
  for (int s2 = 0; s2 < 4; s2++) {
    int b = b0 + ty + s2 * 8;
    int j = j0 + tx;
    if (j < 1000) out[b * NN + 11000 + j] = t[tx][ty + s2 * 8] * 0.25f;
  }
}

extern "C" void kernel_launch(void* const* d_in, const int* in_sizes, int n_in,
                              void* d_out, int out_size, void* d_ws, size_t ws_size,
                              hipStream_t stream) {
  const float* x = (const float*)d_in[0];
  const float* W_ae1 = (const float*)d_in[1];
  const float* b_ae1 = (const float*)d_in[2];
  const float* W_ae2 = (const float*)d_in[3];
  const float* b_ae2 = (const float*)d_in[4];
  const float* w1_vals = (const float*)d_in[5];
  const float* b1 = (const float*)d_in[6];
  const float* w3_vals = (const float*)d_in[7];
  const float* b3 = (const float*)d_in[8];
  const int* src = (const int*)d_in[9];
  const int* w3_cols = (const int*)d_in[14];

  int nnz3 = in_sizes[13];
  int n_fe = nnz3 / 8;

  // Workspace layout (f32 slot offsets). NOTE: bf16 tensors of FC*128 elems
  // occupy 3,584,000 f32 slots (7,168,000 bf16 * 2B / 4B). Round-2 bug was
  // sizing these as 1,792,000 -> sT overlapped xeT -> NaN.
  float* W = (float*)d_ws;
  float* h_raw = W + 0;                                  // 12,800
  float* red = W + 12800;                                // 256
  float* stat = W + 13056;                               // 256
  int* map = (int*)(W + 13312);                          // 57,000 ints -> ends 70,312
  float* xT = W + 70400;                                 // 1,536,000 -> ends 1,606,400
  __hip_bfloat16* sT = (__hip_bfloat16*)(W + 1606400);   // 3,584,000 slots -> ends 5,190,400
  float* xeT = W + 5190400;                              // 7,296,000 -> ends 12,486,400
  float* zT = W + 12486400;                              // 7,168,000 -> ends 19,654,400
  // hfcT reuses zT's region: zT is dead after k_s has produced sT.
  __hip_bfloat16* hfcT = (__hip_bfloat16*)zT;            // needs 3,584,000 slots

  hipMemsetAsync(h_raw, 0, 12800 * sizeof(float), stream);
  hipMemsetAsync(red, 0, 256 * sizeof(float), stream);
  hipMemsetAsync(map, 0xFF, EE * sizeof(int), stream);
  hipMemsetAsync(d_out, 0, (size_t)out_size * sizeof(float), stream);

  k_transpose<<<dim3(NN / 32, BB / 32), dim3(32, 8), 0, stream>>>(x, xT);
  k_ae1<<<dim3(BB, 4), 128, 0, stream>>>(x, W_ae1, h_raw);
  k_build_xe<<<(EE * BB) / 256, 256, 0, stream>>>(xT, src, xeT);
  k_map<<<(n_fe + 255) / 256, 256, 0, stream>>>(w3_cols, map, n_fe);
  k_ae2<<<(FC + 127) / 128, 256, 0, stream>>>(h_raw, b_ae1, W_ae2, b_ae2, zT, red);
  k_stat<<<1, 128, 0, stream>>>(red, stat);
  k_s<<<(FC * BB) / (256 * 8), 256, 0, stream>>>(zT, stat, sT);
  for (int l = 0; l < 4; l++) {
    k_layer1<<<NFN / 2, 256, 0, stream>>>(xeT, w1_vals + (size_t)l * 448000,
                                          b1 + (size_t)l * FC, sT, hfcT);
    k_layer2<<<EE / 2, 256, 0, stream>>>(hfcT, w3_vals + (size_t)l * nnz3,
                                         b3 + (size_t)l * EE, map, src, xeT);
  }
  k_out<<<dim3(32, 4), dim3(32, 8), 0, stream>>>(xeT, (float*)d_out);
}

// Round 4
// 395.227 us; speedup vs baseline: 1.4897x; 1.2113x over previous
//
#include <hip/hip_runtime.h>
#include <hip/hip_bf16.h>
#include <math.h>

#define BB 128
#define NN 12000
#define NIN 4000
#define NFN 7000
#define NOMIC 3600
#define FC 56000
#define EE 57000
#define LAT 100

// ---------------- transpose x (B,N) -> xT (N,B) ----------------
__global__ void k_transpose(const float* __restrict__ x, float* __restrict__ xT) {
  __shared__ float t[32][33];
  int n0 = blockIdx.x * 32, b0 = blockIdx.y * 32;
  int tx = threadIdx.x, ty = threadIdx.y;
#pragma unroll
  for (int s = 0; s < 4; s++) {
    int b = b0 + ty + s * 8;
    int n = n0 + tx;
    t[ty + s * 8][tx] = x[b * NN + n];
  }
  __syncthreads();
#pragma unroll
  for (int s = 0; s < 4; s++) {
    int n = n0 + ty + s * 8;
    int b = b0 + tx;
    xT[n * BB + b] = t[tx][ty + s * 8];
  }
}

// ---------------- AE layer 1: h[k*128+b] += sum over k-chunk of xT*W1 ----------------
// Split-K GEMM: grid (25 j-quads, 20 k-chunks), 128 threads = batch lanes.
// xT read coalesced; W1 read is wave-uniform float4 (scalar cache).
__global__ void k_ae1(const float* __restrict__ xT, const float* __restrict__ W1,
                      float* __restrict__ h) {
  int b = threadIdx.x;
  int j0 = blockIdx.x * 4;
  int k0 = blockIdx.y * 180;
  float acc0 = 0.f, acc1 = 0.f, acc2 = 0.f, acc3 = 0.f;
  const float* xp = &xT[(size_t)k0 * BB + b];
  const float* wp = &W1[(size_t)k0 * LAT + j0];
#pragma unroll 4
  for (int kk = 0; kk < 180; kk++) {
    float xv = xp[kk * BB];
    float4 w = *(const float4*)(wp + kk * LAT);  // (k*100+j0)*4 B: k*400 and j0*16 both 16B-aligned
    acc0 += xv * w.x; acc1 += xv * w.y; acc2 += xv * w.z; acc3 += xv * w.w;
  }
  atomicAdd(&h[(j0 + 0) * BB + b], acc0);
  atomicAdd(&h[(j0 + 1) * BB + b], acc1);
  atomicAdd(&h[(j0 + 2) * BB + b], acc2);
  atomicAdd(&h[(j0 + 3) * BB + b], acc3);
}

// ---------------- build xeT[e*128+b] from xT / src ----------------
__global__ void k_build_xe(const float* __restrict__ xT, const int* __restrict__ src,
                           float* __restrict__ xeT) {
  int idx = blockIdx.x * 256 + threadIdx.x;
  if (idx >= EE * BB) return;
  int e = idx >> 7, b = idx & 127;
  int s = src[e];
  xeT[idx] = (s < NOMIC) ? 0.f : xT[s * BB + b];
}

// ---------------- map[e] = fe-position i (else -1, pre-set by memset 0xFF) ----------------
__global__ void k_map(const int* __restrict__ w3_cols, int* __restrict__ map, int n_fe) {
  int i = blockIdx.x * 256 + threadIdx.x;
  if (i < n_fe) map[w3_cols[i * 8]] = i;
}

// ---------------- AE layer 2 GEMM: zT[j*128+b] = elu(h) @ W2 + b2, + LN partial sums --
__launch_bounds__(256)
__global__ void k_ae2(const float* __restrict__ h_raw, const float* __restrict__ b_ae1,
                      const float* __restrict__ W2, const float* __restrict__ b_ae2,
                      float* __restrict__ zT, float* __restrict__ red) {
  __shared__ __align__(16) float hh[LAT * BB];  // hh[k*128+b], 51.2 KB
  __shared__ float lred[256];
  int tid = threadIdx.x;
  lred[tid] = 0.f;
  // h_raw is already [k*BB + b]
  for (int idx = tid; idx < LAT * BB; idx += 256) {
    float v = h_raw[idx] + b_ae1[idx >> 7];
    v = v > 0.f ? v : expm1f(v);
    hh[idx] = v;
  }
  __syncthreads();

  int tj = tid & 15;
  int tb = tid >> 4;
  int j0 = blockIdx.x * 128;
  if (j0 + 128 > FC) j0 = FC - 128;
  bool cred = (blockIdx.x < 437) || (tj >= 8);

  float acc[8][8];
#pragma unroll
  for (int i = 0; i < 8; i++)
#pragma unroll
    for (int j = 0; j < 8; j++) acc[i][j] = 0.f;

  const float* hp = &hh[tb * 8];
  const float* wp = &W2[j0 + tj * 8];
#pragma unroll 2
  for (int k = 0; k < LAT; k++) {
    float4 h0 = *(const float4*)(hp + k * BB);
    float4 h1 = *(const float4*)(hp + k * BB + 4);
    float4 w0 = *(const float4*)(wp + (size_t)k * FC);
    float4 w1 = *(const float4*)(wp + (size_t)k * FC + 4);
    float ah[8] = {h0.x, h0.y, h0.z, h0.w, h1.x, h1.y, h1.z, h1.w};
    float aw[8] = {w0.x, w0.y, w0.z, w0.w, w1.x, w1.y, w1.z, w1.w};
#pragma unroll
    for (int i = 0; i < 8; i++)
#pragma unroll
      for (int j = 0; j < 8; j++) acc[i][j] += ah[i] * aw[j];
  }

  float4 bb0 = *(const float4*)&b_ae2[j0 + tj * 8];
  float4 bb1 = *(const float4*)&b_ae2[j0 + tj * 8 + 4];
  float bw[8] = {bb0.x, bb0.y, bb0.z, bb0.w, bb1.x, bb1.y, bb1.z, bb1.w};
#pragma unroll
  for (int i = 0; i < 8; i++)
#pragma unroll
    for (int j = 0; j < 8; j++) acc[i][j] += bw[j];

#pragma unroll
  for (int j = 0; j < 8; j++) {
    float4* zp = (float4*)&zT[(size_t)(j0 + tj * 8 + j) * BB + tb * 8];
    zp[0] = make_float4(acc[0][j], acc[1][j], acc[2][j], acc[3][j]);
    zp[1] = make_float4(acc[4][j], acc[5][j], acc[6][j], acc[7][j]);
  }

  if (cred) {
#pragma unroll
    for (int i = 0; i < 8; i++) {
      float s = 0.f, q = 0.f;
#pragma unroll
      for (int j = 0; j < 8; j++) { s += acc[i][j]; q += acc[i][j] * acc[i][j]; }
      int b = tb * 8 + i;
      atomicAdd(&lred[b * 2], s);
      atomicAdd(&lred[b * 2 + 1], q);
    }
  }
  __syncthreads();
  atomicAdd(&red[tid], lred[tid]);
}

// ---------------- stats: mu[b], inv_sigma[b] ----------------
__global__ void k_stat(const float* __restrict__ red, float* __restrict__ stat) {
  int b = threadIdx.x;
  float mu = red[b * 2] * (1.f / FC);
  float var = red[b * 2 + 1] * (1.f / FC) - mu * mu;
  stat[b * 2] = mu;
  stat[b * 2 + 1] = rsqrtf(var + 1e-5f);
}

// ---------------- s = sigmoid(layernorm(z)), bf16 out, 8 elems/thread ----------------
__global__ void k_s(const float* __restrict__ zT, const float* __restrict__ stat,
                    __hip_bfloat16* __restrict__ sT) {
  int base = (blockIdx.x * 256 + threadIdx.x) * 8;
  float4 z0 = *(const float4*)&zT[base];
  float4 z1 = *(const float4*)&zT[base + 4];
  float zv[8] = {z0.x, z0.y, z0.z, z0.w, z1.x, z1.y, z1.z, z1.w};
  union { ushort u[8]; uint4 v; } pk;
  int b0 = base & 127;
#pragma unroll
  for (int i = 0; i < 8; i++) {
    float mu = stat[(b0 + i) * 2];
    float isg = stat[(b0 + i) * 2 + 1];
    float t = (zv[i] - mu) * isg;
    float sv = 1.f / (1.f + expf(-t));
    __hip_bfloat16 hb = __float2bfloat16(sv);
    pk.u[i] = *(ushort*)&hb;
  }
  *(uint4*)&sT[base] = pk.v;
}

// ---------------- layer part 1: hfc = elu(s * groupLN(8x8 matmul(xe) + b1)) ----------------
__launch_bounds__(256)
__global__ void k_layer1(const float* __restrict__ xeT, const float* __restrict__ w1l,
                         const float* __restrict__ b1l, const __hip_bfloat16* __restrict__ sT,
                         __hip_bfloat16* __restrict__ hfcT) {
  __shared__ __align__(16) float wsm[2][64];
  __shared__ float bsm[2][8];
  int tid = threadIdx.x;
  int fs = tid >> 7;
  int b = tid & 127;
  int f = blockIdx.x * 2 + fs;
  if (tid < 128) wsm[tid >> 6][tid & 63] = w1l[blockIdx.x * 128 + tid];
  if (tid >= 128 && tid < 144) {
    int q = tid - 128;
    bsm[q >> 3][q & 7] = b1l[blockIdx.x * 16 + q];
  }
  __syncthreads();
  float xv[8];
#pragma unroll
  for (int k = 0; k < 8; k++) xv[k] = xeT[(f * 8 + k) * BB + b];
  float acc[8];
#pragma unroll
  for (int c = 0; c < 8; c++) acc[c] = bsm[fs][c];
#pragma unroll
  for (int k = 0; k < 8; k++) {
    const float4* wp = (const float4*)&wsm[fs][k * 8];
    float4 w0 = wp[0], w1 = wp[1];
    acc[0] += xv[k] * w0.x; acc[1] += xv[k] * w0.y;
    acc[2] += xv[k] * w0.z; acc[3] += xv[k] * w0.w;
    acc[4] += xv[k] * w1.x; acc[5] += xv[k] * w1.y;
    acc[6] += xv[k] * w1.z; acc[7] += xv[k] * w1.w;
  }
  float mu = 0.f;
#pragma unroll
  for (int c = 0; c < 8; c++) mu += acc[c];
  mu *= 0.125f;
  float var = 0.f;
#pragma unroll
  for (int c = 0; c < 8; c++) { float d = acc[c] - mu; var += d * d; }
  var *= 0.125f;
  float sc = rsqrtf(var + 1e-5f);
#pragma unroll
  for (int c = 0; c < 8; c++) {
    float v = (acc[c] - mu) * sc;
    float sv = __bfloat162float(sT[(f * 8 + c) * BB + b]);
    float hv = sv * v;
    hv = hv > 0.f ? hv : expm1f(hv);
    hfcT[(f * 8 + c) * BB + b] = __float2bfloat16(hv);
  }
}

// ---------------- layer part 2: xe = (fe? dot8(hfc[src], w3) : 0) + b3 + xe ----------------
__launch_bounds__(256)
__global__ void k_layer2(const __hip_bfloat16* __restrict__ hfcT, const float* __restrict__ w3l,
                         const float* __restrict__ b3l, const int* __restrict__ map,
                         const int* __restrict__ src, float* __restrict__ xeT) {
  __shared__ float wsm[2][8];
  int tid = threadIdx.x;
  int es = tid >> 7;
  int b = tid & 127;
  int e = blockIdx.x * 2 + es;
  if (tid < 16) {
    int q = tid;
    int ee = blockIdx.x * 2 + (q >> 3);
    int ii = map[ee];
    wsm[q >> 3][q & 7] = (ii >= 0) ? w3l[ii * 8 + (q & 7)] : 0.f;
  }
  __syncthreads();
  int i = map[e];
  float rv = b3l[e] + xeT[e * BB + b];
  if (i >= 0) {
    int g = src[e] - NIN;
    float a = 0.f;
#pragma unroll
    for (int c = 0; c < 8; c++)
      a += __bfloat162float(hfcT[(g * 8 + c) * BB + b]) * wsm[es][c];
    rv += a;
  }
  xeT[e * BB + b] = rv;
}

// ---------------- output: out[b, 11000+j] = xe[b, 56000+j] / 4 ----------------
__global__ void k_out(const float* __restrict__ xeT, float* __restrict__ out) {
  __shared__ float t[32][33];
  int j0 = blockIdx.x * 32, b0 = blockIdx.y * 32;
  int tx = threadIdx.x, ty = threadIdx.y;
#pragma unroll
  for (int s2 = 0; s2 < 4; s2++) {
    int j = j0 + ty + s2 * 8;
    if (j < 1000) t[ty + s2 * 8][tx] = xeT[(FC + j) * BB + b0 + tx];
  }
  __syncthreads();
#pragma unroll
  for (int s2 = 0; s2 < 4; s2++) {
    int b = b0 + ty + s2 * 8;
    int j = j0 + tx;
    if (j < 1000) out[b * NN + 11000 + j] = t[tx][ty + s2 * 8] * 0.25f;
  }
}

extern "C" void kernel_launch(void* const* d_in, const int* in_sizes, int n_in,
                              void* d_out, int out_size, void* d_ws, size_t ws_size,
                              hipStream_t stream) {
  const float* x = (const float*)d_in[0];
  const float* W_ae1 = (const float*)d_in[1];
  const float* b_ae1 = (const float*)d_in[2];
  const float* W_ae2 = (const float*)d_in[3];
  const float* b_ae2 = (const float*)d_in[4];
  const float* w1_vals = (const float*)d_in[5];
  const float* b1 = (const float*)d_in[6];
  const float* w3_vals = (const float*)d_in[7];
  const float* b3 = (const float*)d_in[8];
  const int* src = (const int*)d_in[9];
  const int* w3_cols = (const int*)d_in[14];

  int nnz3 = in_sizes[13];
  int n_fe = nnz3 / 8;

  float* W = (float*)d_ws;
  float* h_raw = W + 0;                                  // 12,800 (layout [k*128+b])
  float* red = W + 12800;                                // 256
  float* stat = W + 13056;                               // 256
  int* map = (int*)(W + 13312);                          // 57,000 ints -> ends 70,312
  float* xT = W + 70400;                                 // 1,536,000 -> ends 1,606,400
  __hip_bfloat16* sT = (__hip_bfloat16*)(W + 1606400);   // 3,584,000 slots -> ends 5,190,400
  float* xeT = W + 5190400;                              // 7,296,000 -> ends 12,486,400
  float* zT = W + 12486400;                              // 7,168,000 -> ends 19,654,400
  __hip_bfloat16* hfcT = (__hip_bfloat16*)zT;            // reuse (zT dead after k_s)

  hipMemsetAsync(h_raw, 0, 12800 * sizeof(float), stream);
  hipMemsetAsync(red, 0, 256 * sizeof(float), stream);
  hipMemsetAsync(map, 0xFF, EE * sizeof(int), stream);
  hipMemsetAsync(d_out, 0, (size_t)out_size * sizeof(float), stream);

  k_transpose<<<dim3(NN / 32, BB / 32), dim3(32, 8), 0, stream>>>(x, xT);
  k_ae1<<<dim3(25, 20), 128, 0, stream>>>(xT, W_ae1, h_raw);
  k_build_xe<<<(EE * BB) / 256, 256, 0, stream>>>(xT, src, xeT);
  k_map<<<(n_fe + 255) / 256, 256, 0, stream>>>(w3_cols, map, n_fe);
  k_ae2<<<(FC + 127) / 128, 256, 0, stream>>>(h_raw, b_ae1, W_ae2, b_ae2, zT, red);
  k_stat<<<1, 128, 0, stream>>>(red, stat);
  k_s<<<(FC * BB) / (256 * 8), 256, 0, stream>>>(zT, stat, sT);
  for (int l = 0; l < 4; l++) {
    k_layer1<<<NFN / 2, 256, 0, stream>>>(xeT, w1_vals + (size_t)l * 448000,
                                          b1 + (size_t)l * FC, sT, hfcT);
    k_layer2<<<EE / 2, 256, 0, stream>>>(hfcT, w3_vals + (size_t)l * nnz3,
                                         b3 + (size_t)l * EE, map, src, xeT);
  }
  k_out<<<dim3(32, 4), dim3(32, 8), 0, stream>>>(xeT, (float*)d_out);
}

// Round 5
// 375.930 us; speedup vs baseline: 1.5662x; 1.0513x over previous
//
#include <hip/hip_runtime.h>
#include <hip/hip_bf16.h>
#include <math.h>

#define BB 128
#define NN 12000
#define NIN 4000
#define NFN 7000
#define NOMIC 3600
#define FC 56000
#define EE 57000
#define LAT 100

typedef __hip_bfloat16 bf16;

__device__ __forceinline__ ushort f2bf(float f) {
  bf16 h = __float2bfloat16(f);
  return *(ushort*)&h;
}
__device__ __forceinline__ float bf2f(ushort u) {
  bf16 h = *(bf16*)&u;
  return __bfloat162float(h);
}

// ---------------- transpose x (B,N) -> xT (N,B) ----------------
__global__ void k_transpose(const float* __restrict__ x, float* __restrict__ xT) {
  __shared__ float t[32][33];
  int n0 = blockIdx.x * 32, b0 = blockIdx.y * 32;
  int tx = threadIdx.x, ty = threadIdx.y;
#pragma unroll
  for (int s = 0; s < 4; s++) {
    int b = b0 + ty + s * 8;
    int n = n0 + tx;
    t[ty + s * 8][tx] = x[b * NN + n];
  }
  __syncthreads();
#pragma unroll
  for (int s = 0; s < 4; s++) {
    int n = n0 + ty + s * 8;
    int b = b0 + tx;
    xT[n * BB + b] = t[tx][ty + s * 8];
  }
}

// ---------------- AE layer 1: h[j*128+b], split-K, W1 wave-uniform float4 ----------------
__global__ void k_ae1(const float* __restrict__ xT, const float* __restrict__ W1,
                      float* __restrict__ h) {
  int b = threadIdx.x;
  int j0 = blockIdx.x * 4;
  int k0 = blockIdx.y * 180;
  float acc0 = 0.f, acc1 = 0.f, acc2 = 0.f, acc3 = 0.f;
  const float* xp = &xT[(size_t)k0 * BB + b];
  const float* wp = &W1[(size_t)k0 * LAT + j0];
#pragma unroll 4
  for (int kk = 0; kk < 180; kk++) {
    float xv = xp[kk * BB];
    float4 w = *(const float4*)(wp + kk * LAT);
    acc0 += xv * w.x; acc1 += xv * w.y; acc2 += xv * w.z; acc3 += xv * w.w;
  }
  atomicAdd(&h[(j0 + 0) * BB + b], acc0);
  atomicAdd(&h[(j0 + 1) * BB + b], acc1);
  atomicAdd(&h[(j0 + 2) * BB + b], acc2);
  atomicAdd(&h[(j0 + 3) * BB + b], acc3);
}

// ---------------- build xeT (bf16) from xT / src ----------------
__global__ void k_build_xe(const float* __restrict__ xT, const int* __restrict__ src,
                           ushort* __restrict__ xeT) {
  int idx = blockIdx.x * 256 + threadIdx.x;
  if (idx >= EE * BB) return;
  int e = idx >> 7, b = idx & 127;
  int s = src[e];
  xeT[idx] = (s < NOMIC) ? f2bf(0.f) : f2bf(xT[s * BB + b]);
}

// ---------------- map[e] = fe-position i (else -1, pre-set by memset 0xFF) ----------------
__global__ void k_map(const int* __restrict__ w3_cols, int* __restrict__ map, int n_fe) {
  int i = blockIdx.x * 256 + threadIdx.x;
  if (i < n_fe) map[w3_cols[i * 8]] = i;
}

// ---------------- AE layer 2 GEMM: zT(bf16) = elu(h) @ W2 + b2, + LN partial sums --------
// 512 threads: tj = tid>>5 (16 j-octets -> 128 j), tb = tid&31 (32 b-quads -> 128 b).
// W2 loads are wave-broadcast (2 unique j-octets/wave); hh b128 reads conflict-free
// (lanes 0..31 contiguous 16B, lanes 32..63 duplicate = free 2-way); zT stores coalesce
// (32 lanes x 8B contiguous).
__launch_bounds__(512)
__global__ void k_ae2(const float* __restrict__ h_raw, const float* __restrict__ b_ae1,
                      const float* __restrict__ W2, const float* __restrict__ b_ae2,
                      ushort* __restrict__ zT, float* __restrict__ red) {
  __shared__ __align__(16) float hh[LAT * BB];  // 51.2 KB
  __shared__ float lred[256];
  int tid = threadIdx.x;
  if (tid < 256) lred[tid] = 0.f;
  for (int idx = tid; idx < LAT * BB; idx += 512) {
    float v = h_raw[idx] + b_ae1[idx >> 7];
    v = v > 0.f ? v : expm1f(v);
    hh[idx] = v;
  }
  __syncthreads();

  int tj = tid >> 5;   // 0..15
  int tb = tid & 31;   // 0..31
  int j0 = blockIdx.x * 128;
  if (j0 + 128 > FC) j0 = FC - 128;  // last block overlaps
  bool cred = (blockIdx.x < 437) || (tj >= 8);

  float acc[4][8];
#pragma unroll
  for (int i = 0; i < 4; i++)
#pragma unroll
    for (int j = 0; j < 8; j++) acc[i][j] = 0.f;

  const float* hp = &hh[tb * 4];
  const float* wp = &W2[j0 + tj * 8];
#pragma unroll 4
  for (int k = 0; k < LAT; k++) {
    float4 h0 = *(const float4*)(hp + k * BB);
    float4 w0 = *(const float4*)(wp + (size_t)k * FC);
    float4 w1 = *(const float4*)(wp + (size_t)k * FC + 4);
    float ah[4] = {h0.x, h0.y, h0.z, h0.w};
    float aw[8] = {w0.x, w0.y, w0.z, w0.w, w1.x, w1.y, w1.z, w1.w};
#pragma unroll
    for (int i = 0; i < 4; i++)
#pragma unroll
      for (int j = 0; j < 8; j++) acc[i][j] += ah[i] * aw[j];
  }

  float4 bb0 = *(const float4*)&b_ae2[j0 + tj * 8];
  float4 bb1 = *(const float4*)&b_ae2[j0 + tj * 8 + 4];
  float bw[8] = {bb0.x, bb0.y, bb0.z, bb0.w, bb1.x, bb1.y, bb1.z, bb1.w};
#pragma unroll
  for (int i = 0; i < 4; i++)
#pragma unroll
    for (int j = 0; j < 8; j++) acc[i][j] += bw[j];

  // store zT as bf16, 4 b per thread -> ushort4 (8B) coalesced across tb
#pragma unroll
  for (int j = 0; j < 8; j++) {
    ushort4 pk;
    pk.x = f2bf(acc[0][j]); pk.y = f2bf(acc[1][j]);
    pk.z = f2bf(acc[2][j]); pk.w = f2bf(acc[3][j]);
    *(ushort4*)&zT[(size_t)(j0 + tj * 8 + j) * BB + tb * 4] = pk;
  }

  if (cred) {
#pragma unroll
    for (int i = 0; i < 4; i++) {
      float s = 0.f, q = 0.f;
#pragma unroll
      for (int j = 0; j < 8; j++) { s += acc[i][j]; q += acc[i][j] * acc[i][j]; }
      int b = tb * 4 + i;
      atomicAdd(&lred[b * 2], s);
      atomicAdd(&lred[b * 2 + 1], q);
    }
  }
  __syncthreads();
  if (tid < 256) atomicAdd(&red[tid], lred[tid]);
}

// ---------------- stats: mu[b], inv_sigma[b] ----------------
__global__ void k_stat(const float* __restrict__ red, float* __restrict__ stat) {
  int b = threadIdx.x;
  float mu = red[b * 2] * (1.f / FC);
  float var = red[b * 2 + 1] * (1.f / FC) - mu * mu;
  stat[b * 2] = mu;
  stat[b * 2 + 1] = rsqrtf(var + 1e-5f);
}

// ---------------- s = sigmoid(layernorm(z)), bf16 in/out, 8 elems/thread ----------------
__global__ void k_s(const ushort* __restrict__ zT, const float* __restrict__ stat,
                    ushort* __restrict__ sT) {
  int base = (blockIdx.x * 256 + threadIdx.x) * 8;
  union { ushort u[8]; uint4 v; } zin;
  zin.v = *(const uint4*)&zT[base];
  union { ushort u[8]; uint4 v; } pk;
  int b0 = base & 127;
#pragma unroll
  for (int i = 0; i < 8; i++) {
    float mu = stat[(b0 + i) * 2];
    float isg = stat[(b0 + i) * 2 + 1];
    float t = (bf2f(zin.u[i]) - mu) * isg;
    pk.u[i] = f2bf(1.f / (1.f + expf(-t)));
  }
  *(uint4*)&sT[base] = pk.v;
}

// ---------------- layer part 1: hfc = elu(s * groupLN(8x8 matmul(xe) + b1)) ----------------
__launch_bounds__(256)
__global__ void k_layer1(const ushort* __restrict__ xeT, const float* __restrict__ w1l,
                         const float* __restrict__ b1l, const ushort* __restrict__ sT,
                         ushort* __restrict__ hfcT) {
  __shared__ __align__(16) float wsm[2][64];
  __shared__ float bsm[2][8];
  int tid = threadIdx.x;
  int fs = tid >> 7;
  int b = tid & 127;
  int f = blockIdx.x * 2 + fs;
  if (tid < 128) wsm[tid >> 6][tid & 63] = w1l[blockIdx.x * 128 + tid];
  if (tid >= 128 && tid < 144) {
    int q = tid - 128;
    bsm[q >> 3][q & 7] = b1l[blockIdx.x * 16 + q];
  }
  __syncthreads();
  float xv[8];
#pragma unroll
  for (int k = 0; k < 8; k++) xv[k] = bf2f(xeT[(f * 8 + k) * BB + b]);
  float acc[8];
#pragma unroll
  for (int c = 0; c < 8; c++) acc[c] = bsm[fs][c];
#pragma unroll
  for (int k = 0; k < 8; k++) {
    const float4* wp = (const float4*)&wsm[fs][k * 8];
    float4 w0 = wp[0], w1 = wp[1];
    acc[0] += xv[k] * w0.x; acc[1] += xv[k] * w0.y;
    acc[2] += xv[k] * w0.z; acc[3] += xv[k] * w0.w;
    acc[4] += xv[k] * w1.x; acc[5] += xv[k] * w1.y;
    acc[6] += xv[k] * w1.z; acc[7] += xv[k] * w1.w;
  }
  float mu = 0.f;
#pragma unroll
  for (int c = 0; c < 8; c++) mu += acc[c];
  mu *= 0.125f;
  float var = 0.f;
#pragma unroll
  for (int c = 0; c < 8; c++) { float d = acc[c] - mu; var += d * d; }
  var *= 0.125f;
  float sc = rsqrtf(var + 1e-5f);
#pragma unroll
  for (int c = 0; c < 8; c++) {
    float v = (acc[c] - mu) * sc;
    float sv = bf2f(sT[(f * 8 + c) * BB + b]);
    float hv = sv * v;
    hv = hv > 0.f ? hv : expm1f(hv);
    hfcT[(f * 8 + c) * BB + b] = f2bf(hv);
  }
}

// ---------------- layer part 2: xe = (fe? dot8(hfc[src], w3) : 0) + b3 + xe ----------------
__launch_bounds__(256)
__global__ void k_layer2(const ushort* __restrict__ hfcT, const float* __restrict__ w3l,
                         const float* __restrict__ b3l, const int* __restrict__ map,
                         const int* __restrict__ src, ushort* __restrict__ xeT) {
  __shared__ float wsm[2][8];
  int tid = threadIdx.x;
  int es = tid >> 7;
  int b = tid & 127;
  int e = blockIdx.x * 2 + es;
  if (tid < 16) {
    int q = tid;
    int ee = blockIdx.x * 2 + (q >> 3);
    int ii = map[ee];
    wsm[q >> 3][q & 7] = (ii >= 0) ? w3l[ii * 8 + (q & 7)] : 0.f;
  }
  __syncthreads();
  int i = map[e];
  float rv = b3l[e] + bf2f(xeT[e * BB + b]);
  if (i >= 0) {
    int g = src[e] - NIN;
    float a = 0.f;
#pragma unroll
    for (int c = 0; c < 8; c++)
      a += bf2f(hfcT[(g * 8 + c) * BB + b]) * wsm[es][c];
    rv += a;
  }
  xeT[e * BB + b] = f2bf(rv);
}

// ---------------- output: out[b, 11000+j] = xe[b, 56000+j] / 4 ----------------
__global__ void k_out(const ushort* __restrict__ xeT, float* __restrict__ out) {
  __shared__ float t[32][33];
  int j0 = blockIdx.x * 32, b0 = blockIdx.y * 32;
  int tx = threadIdx.x, ty = threadIdx.y;
#pragma unroll
  for (int s2 = 0; s2 < 4; s2++) {
    int j = j0 + ty + s2 * 8;
    if (j < 1000) t[ty + s2 * 8][tx] = bf2f(xeT[(FC + j) * BB + b0 + tx]);
  }
  __syncthreads();
#pragma unroll
  for (int s2 = 0; s2 < 4; s2++) {
    int b = b0 + ty + s2 * 8;
    int j = j0 + tx;
    if (j < 1000) out[b * NN + 11000 + j] = t[tx][ty + s2 * 8] * 0.25f;
  }
}

extern "C" void kernel_launch(void* const* d_in, const int* in_sizes, int n_in,
                              void* d_out, int out_size, void* d_ws, size_t ws_size,
                              hipStream_t stream) {
  const float* x = (const float*)d_in[0];
  const float* W_ae1 = (const float*)d_in[1];
  const float* b_ae1 = (const float*)d_in[2];
  const float* W_ae2 = (const float*)d_in[3];
  const float* b_ae2 = (const float*)d_in[4];
  const float* w1_vals = (const float*)d_in[5];
  const float* b1 = (const float*)d_in[6];
  const float* w3_vals = (const float*)d_in[7];
  const float* b3 = (const float*)d_in[8];
  const int* src = (const int*)d_in[9];
  const int* w3_cols = (const int*)d_in[14];

  int nnz3 = in_sizes[13];
  int n_fe = nnz3 / 8;

  // Workspace layout (f32 slot offsets); bf16 tensors occupy elems/2 slots.
  float* W = (float*)d_ws;
  float* h_raw = W + 0;                         // 12,800  [j*128+b]
  float* red = W + 12800;                       // 256
  float* stat = W + 13056;                      // 256
  int* map = (int*)(W + 13312);                 // 57,000 ints -> ends 70,312
  float* xT = W + 70400;                        // 1,536,000 -> ends 1,606,400
  ushort* sT = (ushort*)(W + 1606400);          // 7,168,000 bf16 = 3,584,000 -> ends 5,190,400
  ushort* xeT = (ushort*)(W + 5190400);         // 7,296,000 bf16 = 3,648,000 -> ends 8,838,400
  ushort* zT = (ushort*)(W + 8838400);          // 7,168,000 bf16 = 3,584,000 -> ends 12,422,400
  ushort* hfcT = zT;                            // reuse (zT dead after k_s)

  hipMemsetAsync(h_raw, 0, 13312 * sizeof(float), stream);  // h_raw + red + stat
  hipMemsetAsync(map, 0xFF, EE * sizeof(int), stream);
  hipMemsetAsync(d_out, 0, (size_t)out_size * sizeof(float), stream);

  k_transpose<<<dim3(NN / 32, BB / 32), dim3(32, 8), 0, stream>>>(x, xT);
  k_ae1<<<dim3(25, 20), 128, 0, stream>>>(xT, W_ae1, h_raw);
  k_build_xe<<<(EE * BB) / 256, 256, 0, stream>>>(xT, src, xeT);
  k_map<<<(n_fe + 255) / 256, 256, 0, stream>>>(w3_cols, map, n_fe);
  k_ae2<<<(FC + 127) / 128, 512, 0, stream>>>(h_raw, b_ae1, W_ae2, b_ae2, zT, red);
  k_stat<<<1, 128, 0, stream>>>(red, stat);
  k_s<<<(FC * BB) / (256 * 8), 256, 0, stream>>>(zT, stat, sT);
  for (int l = 0; l < 4; l++) {
    k_layer1<<<NFN / 2, 256, 0, stream>>>(xeT, w1_vals + (size_t)l * 448000,
                                          b1 + (size_t)l * FC, sT, hfcT);
    k_layer2<<<EE / 2, 256, 0, stream>>>(hfcT, w3_vals + (size_t)l * nnz3,
                                         b3 + (size_t)l * EE, map, src, xeT);
  }
  k_out<<<dim3(32, 4), dim3(32, 8), 0, stream>>>(xeT, (float*)d_out);
}